// Round 4
// baseline (2307.254 us; speedup 1.0000x reference)
//
#include <hip/hip_runtime.h>

typedef _Float16 half8 __attribute__((ext_vector_type(8)));
typedef _Float16 half4 __attribute__((ext_vector_type(4)));
typedef float f32x4 __attribute__((ext_vector_type(4)));
typedef unsigned long long ull;

#define SCOPE __HIP_MEMORY_SCOPE_AGENT

// B=16, T=64, L=64, H=256. K=2H=512, N=4H=1024. W shared across layers/time.
// ws: flags[64][4] epoch counters (int, = completed timesteps for (l,r) slice),
//     then f16 h buffer: 2 slots * 64 l * 16 b * 256 u (ping-pong on t&1).
constexpr size_t OFF_FLAGS = 0;
constexpr size_t OFF_H     = 65536;

__device__ __forceinline__ size_t Hidx(int slot, int l, int b, int u) {
  return (((size_t)slot * 64 + l) * 16 + b) * 256 + u;
}
__device__ __forceinline__ float sigm(float v) { return 1.0f / (1.0f + __expf(-v)); }
__device__ __forceinline__ float tanh_(float v) { return 1.0f - 2.0f / (__expf(2.0f * v) + 1.0f); }

__global__ void init_ws(const float* __restrict__ init_state, char* ws) {
  int* flags = (int*)(ws + OFF_FLAGS);
  _Float16* Hp = (_Float16*)(ws + OFF_H);
  const int tid = blockIdx.x * 256 + threadIdx.x;  // 65536 threads
  if (tid < 4096) flags[tid] = 0;
  for (int e = tid; e < 64 * 16 * 256; e += 65536) {
    const int u = e & 255, b = (e >> 8) & 15, l = e >> 12;
    Hp[Hidx(1, l, b, u)] = (_Float16)init_state[((l * 2 + 1) * 16 + b) * 256 + u];
  }
}

// 256 WGs = (layer l = wg>>2, col-slice r = wg&3); 1 block/CU, co-resident.
__global__ __launch_bounds__(256, 1) void lstm_mfma(
    const float* __restrict__ x, const float* __restrict__ init_state,
    const float* __restrict__ W, const float* __restrict__ bias,
    float* __restrict__ out, char* ws) {
  int* flags = (int*)(ws + OFF_FLAGS);
  ull* fl64 = (ull*)flags;
  ull* Hp64 = (ull*)(ws + OFF_H);

  const int tid = threadIdx.x;
  const int wg = blockIdx.x;
  const int l = wg >> 2, r = wg & 3;
  const int wv = tid >> 6, lane = tid & 63;
  const int m = lane & 15, ksub = (lane >> 4) * 8;

  __shared__ alignas(16) float smemRaw[32 * 257];  // 32.9 KB, reused
  float* wstage = smemRaw;                         // prologue W bounce
  float* zLds = smemRaw;                           // steady state: [b*260 + nl]

  // ---- W prologue: coalesced global -> LDS chunk -> f16 B-frags in registers.
  // B-frag (mfma_f32_16x16x32_f16): lane holds B[k=(lane>>4)*8+jj][n=lane&15].
  // Slice-local col nl = j*4 + g; global col = g*256 + r*64 + j.
  half8 wreg[64];  // [q*16 + kb]
  for (int c = 0; c < 16; ++c) {  // chunk c == kb, rows k = c*32 .. c*32+31
    const float* Wc = W + (size_t)(c * 32) * 1024 + (tid >> 6) * 256 + r * 64 + (tid & 63);
#pragma unroll
    for (int rr = 0; rr < 32; ++rr)
      wstage[rr * 257 + tid] = Wc[(size_t)rr * 1024];
    __syncthreads();
#pragma unroll
    for (int q = 0; q < 4; ++q) {
      const int nl = (wv * 4 + q) * 16 + (lane & 15);
      const int pos = (nl & 3) * 64 + (nl >> 2);
      half8 hv;
#pragma unroll
      for (int jj = 0; jj < 8; ++jj)
        hv[jj] = (_Float16)wstage[(ksub + jj) * 257 + pos];
      wreg[q * 16 + c] = hv;
    }
    __syncthreads();
  }

  // ---- epilogue identity: batch eb = tid>>4, units gu0..gu0+3 ----
  const int eb = tid >> 4;
  const int ju = (tid & 15) * 4;      // unit group within slice
  const int gu0 = r * 64 + ju;        // global unit
  f32x4 creg = *(const f32x4*)(init_state + ((l * 2 + 0) * 16 + eb) * 256 + gu0);
  const f32x4 bI = *(const f32x4*)(bias + 0 * 256 + gu0);
  const f32x4 bJ = *(const f32x4*)(bias + 1 * 256 + gu0);
  const f32x4 bF = *(const f32x4*)(bias + 2 * 256 + gu0);
  const f32x4 bO = *(const f32x4*)(bias + 3 * 256 + gu0);

  for (int t = 0; t < 64; ++t) {
    const int slotCur = t & 1, slotPrev = (t + 1) & 1;

    // ---- poll producer (epoch>=t+1) + sibling (epoch>=t), overlapped 8B loads ----
    if (l > 0 || t > 0) {
      const int pi = (l - 1) * 2, si = l * 2;
      for (int it = 0; it < (1 << 22); ++it) {
        bool ok = true;
        if (l > 0) {
          ull p0 = __hip_atomic_load(fl64 + pi, __ATOMIC_RELAXED, SCOPE);
          ull p1 = __hip_atomic_load(fl64 + pi + 1, __ATOMIC_RELAXED, SCOPE);
          const int need = t + 1;
          ok &= ((int)p0 >= need) & ((int)(p0 >> 32) >= need) &
                ((int)p1 >= need) & ((int)(p1 >> 32) >= need);
        }
        if (t > 0) {
          ull s0 = __hip_atomic_load(fl64 + si, __ATOMIC_RELAXED, SCOPE);
          ull s1 = __hip_atomic_load(fl64 + si + 1, __ATOMIC_RELAXED, SCOPE);
          ok &= ((int)s0 >= t) & ((int)(s0 >> 32) >= t) &
                ((int)s1 >= t) & ((int)(s1 >> 32) >= t);
        }
        if (ok) break;
        __builtin_amdgcn_s_sleep(1);
      }
    }

    // ---- early back-pressure load (checked before publish; counter monotonic) ----
    const bool bpNeed = (l < 63) && (t >= 2);
    ull bp0 = 0, bp1 = 0;
    if (bpNeed) {
      bp0 = __hip_atomic_load(fl64 + (l + 1) * 2, __ATOMIC_RELAXED, SCOPE);
      bp1 = __hip_atomic_load(fl64 + (l + 1) * 2 + 1, __ATOMIC_RELAXED, SCOPE);
    }

    // ---- A-frags direct to registers: lane needs A[m][k0..k0+7] per kb ----
    half8 afrag[16];
    if (l == 0) {
      const float* xb = x + ((size_t)m * 64 + t) * 256;
#pragma unroll
      for (int kb = 0; kb < 8; ++kb) {
        const int k0 = kb * 32 + ksub;
        f32x4 x0 = *(const f32x4*)(xb + k0);
        f32x4 x1 = *(const f32x4*)(xb + k0 + 4);
        half8 hv;
#pragma unroll
        for (int jj = 0; jj < 4; ++jj) {
          hv[jj] = (_Float16)x0[jj];
          hv[4 + jj] = (_Float16)x1[jj];
        }
        afrag[kb] = hv;
      }
    } else {
#pragma unroll
      for (int kb = 0; kb < 8; ++kb) {
        const size_t o = Hidx(slotCur, l - 1, m, kb * 32 + ksub) >> 2;
        ull a0 = __hip_atomic_load(Hp64 + o, __ATOMIC_RELAXED, SCOPE);
        ull a1 = __hip_atomic_load(Hp64 + o + 1, __ATOMIC_RELAXED, SCOPE);
        half8 hv;
        ((ull*)&hv)[0] = a0;
        ((ull*)&hv)[1] = a1;
        afrag[kb] = hv;
      }
    }
#pragma unroll
    for (int kb = 8; kb < 16; ++kb) {
      const size_t o = Hidx(slotPrev, l, m, (kb - 8) * 32 + ksub) >> 2;
      ull a0 = __hip_atomic_load(Hp64 + o, __ATOMIC_RELAXED, SCOPE);
      ull a1 = __hip_atomic_load(Hp64 + o + 1, __ATOMIC_RELAXED, SCOPE);
      half8 hv;
      ((ull*)&hv)[0] = a0;
      ((ull*)&hv)[1] = a1;
      afrag[kb] = hv;
    }

    // ---- GEMM: z[16 x 256] = A[16x512] * Wslice[512x256] ----
    f32x4 acc[4] = {{0.f, 0.f, 0.f, 0.f}, {0.f, 0.f, 0.f, 0.f},
                    {0.f, 0.f, 0.f, 0.f}, {0.f, 0.f, 0.f, 0.f}};
#pragma unroll
    for (int kb = 0; kb < 16; ++kb) {
#pragma unroll
      for (int q = 0; q < 4; ++q)
        acc[q] = __builtin_amdgcn_mfma_f32_16x16x32_f16(afrag[kb], wreg[q * 16 + kb], acc[q], 0, 0, 0);
    }

    // ---- z -> LDS (C layout: n=lane&15, mrow=(lane>>4)*4+rg) ----
#pragma unroll
    for (int q = 0; q < 4; ++q) {
      const int nl = (wv * 4 + q) * 16 + (lane & 15);
      const int m0 = (lane >> 4) * 4;
#pragma unroll
      for (int rg = 0; rg < 4; ++rg) zLds[(m0 + rg) * 260 + nl] = acc[q][rg];
    }
    __syncthreads();

    // ---- back-pressure final check (gates slot overwrite) ----
    if (bpNeed) {
      const int need = t - 1;
      bool ok = ((int)bp0 >= need) & ((int)(bp0 >> 32) >= need) &
                ((int)bp1 >= need) & ((int)(bp1 >> 32) >= need);
      if (!ok) {
        for (int it = 0; it < (1 << 22); ++it) {
          bp0 = __hip_atomic_load(fl64 + (l + 1) * 2, __ATOMIC_RELAXED, SCOPE);
          bp1 = __hip_atomic_load(fl64 + (l + 1) * 2 + 1, __ATOMIC_RELAXED, SCOPE);
          ok = ((int)bp0 >= need) & ((int)(bp0 >> 32) >= need) &
               ((int)bp1 >= need) & ((int)(bp1 >> 32) >= need);
          if (ok) break;
          __builtin_amdgcn_s_sleep(1);
        }
      }
    }

    // ---- LSTM epilogue: (eb, units ju..ju+3); gates contiguous in zLds ----
    const float* zb = &zLds[eb * 260 + ju * 4];
    f32x4 zz[4];
    zz[0] = *(const f32x4*)(zb + 0);
    zz[1] = *(const f32x4*)(zb + 4);
    zz[2] = *(const f32x4*)(zb + 8);
    zz[3] = *(const f32x4*)(zb + 12);
    half4 nhv;
    f32x4 outv;
#pragma unroll
    for (int jj = 0; jj < 4; ++jj) {
      const float iv = zz[jj][0] + bI[jj];
      const float jv = zz[jj][1] + bJ[jj];
      const float fv = zz[jj][2] + bF[jj];
      const float ov = zz[jj][3] + bO[jj];
      const float nc = sigm(fv + 1.0f) * creg[jj] + sigm(iv) * tanh_(jv);
      const float nh = sigm(ov) * tanh_(nc);
      creg[jj] = nc;
      nhv[jj] = (_Float16)nh;
      outv[jj] = nh;
    }
    union { half4 h; ull u; } pu;
    pu.h = nhv;
    __hip_atomic_store(Hp64 + (Hidx(slotCur, l, eb, gu0) >> 2), pu.u,
                       __ATOMIC_RELAXED, SCOPE);
    if (l == 63) *(f32x4*)(out + ((size_t)eb * 64 + t) * 256 + gu0) = outv;
    __syncthreads();  // drains vmcnt: all publish stores acked before flag

    if (tid == 0)
      __hip_atomic_store(&flags[l * 4 + r], t + 1, __ATOMIC_RELEASE, SCOPE);
  }
}

extern "C" void kernel_launch(void* const* d_in, const int* in_sizes, int n_in,
                              void* d_out, int out_size, void* d_ws,
                              size_t ws_size, hipStream_t stream) {
  const float* x          = (const float*)d_in[0];
  const float* init_state = (const float*)d_in[1];
  const float* W          = (const float*)d_in[2];
  const float* bias       = (const float*)d_in[3];
  float* out = (float*)d_out;
  char* ws   = (char*)d_ws;

  init_ws<<<256, 256, 0, stream>>>(init_state, ws);
  lstm_mfma<<<256, 256, 0, stream>>>(x, init_state, W, bias, out, ws);
}

// Round 5
// 1364.834 us; speedup vs baseline: 1.6905x; 1.6905x over previous
//
#include <hip/hip_runtime.h>

typedef _Float16 half8 __attribute__((ext_vector_type(8)));
typedef _Float16 half4 __attribute__((ext_vector_type(4)));
typedef float f32x4 __attribute__((ext_vector_type(4)));
typedef unsigned long long ull;

#define SCOPE __HIP_MEMORY_SCOPE_AGENT

// B=16, T=64, L=64, H=256. K=2H=512, N=4H=1024. W shared across layers/time.
// ws: flags[64][4] epoch counters (int, = completed timesteps for (l,r) slice),
//     then f16 h buffer: 2 slots * 64 l * 16 b * 256 u (ping-pong on t&1).
constexpr size_t OFF_FLAGS = 0;
constexpr size_t OFF_H     = 65536;

__device__ __forceinline__ size_t Hidx(int slot, int l, int b, int u) {
  return (((size_t)slot * 64 + l) * 16 + b) * 256 + u;
}
__device__ __forceinline__ float sigm(float v) { return 1.0f / (1.0f + __expf(-v)); }
__device__ __forceinline__ float tanh_(float v) { return 1.0f - 2.0f / (__expf(2.0f * v) + 1.0f); }

__global__ void init_ws(const float* __restrict__ init_state, char* ws) {
  int* flags = (int*)(ws + OFF_FLAGS);
  _Float16* Hp = (_Float16*)(ws + OFF_H);
  const int tid = blockIdx.x * 256 + threadIdx.x;  // 65536 threads
  if (tid < 4096) flags[tid] = 0;
  for (int e = tid; e < 64 * 16 * 256; e += 65536) {
    const int u = e & 255, b = (e >> 8) & 15, l = e >> 12;
    Hp[Hidx(1, l, b, u)] = (_Float16)init_state[((l * 2 + 1) * 16 + b) * 256 + u];
  }
}

// 256 WGs = (layer l = wg>>2, col-slice r = wg&3); 1 block/CU, co-resident.
__global__ __launch_bounds__(256, 1) void lstm_mfma(
    const float* __restrict__ x, const float* __restrict__ init_state,
    const float* __restrict__ W, const float* __restrict__ bias,
    float* __restrict__ out, char* ws) {
  int* flags = (int*)(ws + OFF_FLAGS);
  ull* fl64 = (ull*)flags;
  ull* Hp64 = (ull*)(ws + OFF_H);

  const int tid = threadIdx.x;
  const int wg = blockIdx.x;
  const int l = wg >> 2, r = wg & 3;
  const int wv = tid >> 6, lane = tid & 63;
  const int m = lane & 15, ksub = (lane >> 4) * 8;

  __shared__ alignas(16) float smemRaw[32 * 257];  // 32.9 KB, reused
  float* wstage = smemRaw;                         // prologue W bounce
  float* zLds = smemRaw;                           // steady state: [b*260 + nl]

  // ---- W prologue: coalesced global -> LDS chunk -> f16 B-frags in registers.
  // B-frag (mfma_f32_16x16x32_f16): lane holds B[k=(lane>>4)*8+jj][n=lane&15].
  // Slice-local col nl = j*4 + g; global col = g*256 + r*64 + j.
  // NOTE: the chunk loop MUST be fully unrolled — a runtime index into wreg
  // demotes the array to scratch (round-4: VGPR 76, 1.75 GB scratch traffic, 3x).
  half8 wreg[64];  // [q*16 + kb]
#pragma unroll
  for (int c = 0; c < 16; ++c) {  // chunk c == kb, rows k = c*32 .. c*32+31
    const float* Wc = W + (size_t)(c * 32) * 1024 + (tid >> 6) * 256 + r * 64 + (tid & 63);
#pragma unroll
    for (int rr = 0; rr < 32; ++rr)
      wstage[rr * 257 + tid] = Wc[(size_t)rr * 1024];
    __syncthreads();
#pragma unroll
    for (int q = 0; q < 4; ++q) {
      const int nl = (wv * 4 + q) * 16 + (lane & 15);
      const int pos = (nl & 3) * 64 + (nl >> 2);
      half8 hv;
#pragma unroll
      for (int jj = 0; jj < 8; ++jj)
        hv[jj] = (_Float16)wstage[(ksub + jj) * 257 + pos];
      wreg[q * 16 + c] = hv;
    }
    __syncthreads();
  }

  // ---- epilogue identity: batch eb = tid>>4, units gu0..gu0+3 ----
  const int eb = tid >> 4;
  const int ju = (tid & 15) * 4;      // unit group within slice
  const int gu0 = r * 64 + ju;        // global unit
  f32x4 creg = *(const f32x4*)(init_state + ((l * 2 + 0) * 16 + eb) * 256 + gu0);
  const f32x4 bI = *(const f32x4*)(bias + 0 * 256 + gu0);
  const f32x4 bJ = *(const f32x4*)(bias + 1 * 256 + gu0);
  const f32x4 bF = *(const f32x4*)(bias + 2 * 256 + gu0);
  const f32x4 bO = *(const f32x4*)(bias + 3 * 256 + gu0);

  for (int t = 0; t < 64; ++t) {
    const int slotCur = t & 1, slotPrev = (t + 1) & 1;

    // ---- poll producer (epoch>=t+1) + sibling (epoch>=t), overlapped 8B loads ----
    if (l > 0 || t > 0) {
      const int pi = (l - 1) * 2, si = l * 2;
      for (int it = 0; it < (1 << 22); ++it) {
        bool ok = true;
        if (l > 0) {
          ull p0 = __hip_atomic_load(fl64 + pi, __ATOMIC_RELAXED, SCOPE);
          ull p1 = __hip_atomic_load(fl64 + pi + 1, __ATOMIC_RELAXED, SCOPE);
          const int need = t + 1;
          ok &= ((int)p0 >= need) & ((int)(p0 >> 32) >= need) &
                ((int)p1 >= need) & ((int)(p1 >> 32) >= need);
        }
        if (t > 0) {
          ull s0 = __hip_atomic_load(fl64 + si, __ATOMIC_RELAXED, SCOPE);
          ull s1 = __hip_atomic_load(fl64 + si + 1, __ATOMIC_RELAXED, SCOPE);
          ok &= ((int)s0 >= t) & ((int)(s0 >> 32) >= t) &
                ((int)s1 >= t) & ((int)(s1 >> 32) >= t);
        }
        if (ok) break;
        __builtin_amdgcn_s_sleep(1);
      }
    }

    // ---- early back-pressure load (checked before publish; counter monotonic) ----
    const bool bpNeed = (l < 63) && (t >= 2);
    ull bp0 = 0, bp1 = 0;
    if (bpNeed) {
      bp0 = __hip_atomic_load(fl64 + (l + 1) * 2, __ATOMIC_RELAXED, SCOPE);
      bp1 = __hip_atomic_load(fl64 + (l + 1) * 2 + 1, __ATOMIC_RELAXED, SCOPE);
    }

    // ---- A-frags direct to registers: lane needs A[m][k0..k0+7] per kb ----
    half8 afrag[16];
    if (l == 0) {
      const float* xb = x + ((size_t)m * 64 + t) * 256;
#pragma unroll
      for (int kb = 0; kb < 8; ++kb) {
        const int k0 = kb * 32 + ksub;
        f32x4 x0 = *(const f32x4*)(xb + k0);
        f32x4 x1 = *(const f32x4*)(xb + k0 + 4);
        half8 hv;
#pragma unroll
        for (int jj = 0; jj < 4; ++jj) {
          hv[jj] = (_Float16)x0[jj];
          hv[4 + jj] = (_Float16)x1[jj];
        }
        afrag[kb] = hv;
      }
    } else {
#pragma unroll
      for (int kb = 0; kb < 8; ++kb) {
        const size_t o = Hidx(slotCur, l - 1, m, kb * 32 + ksub) >> 2;
        ull a0 = __hip_atomic_load(Hp64 + o, __ATOMIC_RELAXED, SCOPE);
        ull a1 = __hip_atomic_load(Hp64 + o + 1, __ATOMIC_RELAXED, SCOPE);
        half8 hv;
        ((ull*)&hv)[0] = a0;
        ((ull*)&hv)[1] = a1;
        afrag[kb] = hv;
      }
    }
#pragma unroll
    for (int kb = 8; kb < 16; ++kb) {
      const size_t o = Hidx(slotPrev, l, m, (kb - 8) * 32 + ksub) >> 2;
      ull a0 = __hip_atomic_load(Hp64 + o, __ATOMIC_RELAXED, SCOPE);
      ull a1 = __hip_atomic_load(Hp64 + o + 1, __ATOMIC_RELAXED, SCOPE);
      half8 hv;
      ((ull*)&hv)[0] = a0;
      ((ull*)&hv)[1] = a1;
      afrag[kb] = hv;
    }

    // ---- GEMM: z[16 x 256] = A[16x512] * Wslice[512x256] ----
    f32x4 acc[4] = {{0.f, 0.f, 0.f, 0.f}, {0.f, 0.f, 0.f, 0.f},
                    {0.f, 0.f, 0.f, 0.f}, {0.f, 0.f, 0.f, 0.f}};
#pragma unroll
    for (int kb = 0; kb < 16; ++kb) {
#pragma unroll
      for (int q = 0; q < 4; ++q)
        acc[q] = __builtin_amdgcn_mfma_f32_16x16x32_f16(afrag[kb], wreg[q * 16 + kb], acc[q], 0, 0, 0);
    }

    // ---- z -> LDS (C layout: n=lane&15, mrow=(lane>>4)*4+rg) ----
#pragma unroll
    for (int q = 0; q < 4; ++q) {
      const int nl = (wv * 4 + q) * 16 + (lane & 15);
      const int m0 = (lane >> 4) * 4;
#pragma unroll
      for (int rg = 0; rg < 4; ++rg) zLds[(m0 + rg) * 260 + nl] = acc[q][rg];
    }
    __syncthreads();

    // ---- back-pressure final check (gates slot overwrite) ----
    if (bpNeed) {
      const int need = t - 1;
      bool ok = ((int)bp0 >= need) & ((int)(bp0 >> 32) >= need) &
                ((int)bp1 >= need) & ((int)(bp1 >> 32) >= need);
      if (!ok) {
        for (int it = 0; it < (1 << 22); ++it) {
          bp0 = __hip_atomic_load(fl64 + (l + 1) * 2, __ATOMIC_RELAXED, SCOPE);
          bp1 = __hip_atomic_load(fl64 + (l + 1) * 2 + 1, __ATOMIC_RELAXED, SCOPE);
          ok = ((int)bp0 >= need) & ((int)(bp0 >> 32) >= need) &
               ((int)bp1 >= need) & ((int)(bp1 >> 32) >= need);
          if (ok) break;
          __builtin_amdgcn_s_sleep(1);
        }
      }
    }

    // ---- LSTM epilogue: (eb, units ju..ju+3); gates contiguous in zLds ----
    const float* zb = &zLds[eb * 260 + ju * 4];
    f32x4 zz[4];
    zz[0] = *(const f32x4*)(zb + 0);
    zz[1] = *(const f32x4*)(zb + 4);
    zz[2] = *(const f32x4*)(zb + 8);
    zz[3] = *(const f32x4*)(zb + 12);
    half4 nhv;
    f32x4 outv;
#pragma unroll
    for (int jj = 0; jj < 4; ++jj) {
      const float iv = zz[jj][0] + bI[jj];
      const float jv = zz[jj][1] + bJ[jj];
      const float fv = zz[jj][2] + bF[jj];
      const float ov = zz[jj][3] + bO[jj];
      const float nc = sigm(fv + 1.0f) * creg[jj] + sigm(iv) * tanh_(jv);
      const float nh = sigm(ov) * tanh_(nc);
      creg[jj] = nc;
      nhv[jj] = (_Float16)nh;
      outv[jj] = nh;
    }
    union { half4 h; ull u; } pu;
    pu.h = nhv;
    __hip_atomic_store(Hp64 + (Hidx(slotCur, l, eb, gu0) >> 2), pu.u,
                       __ATOMIC_RELAXED, SCOPE);
    if (l == 63) *(f32x4*)(out + ((size_t)eb * 64 + t) * 256 + gu0) = outv;
    __syncthreads();  // drains vmcnt: all publish stores acked before flag

    if (tid == 0)
      __hip_atomic_store(&flags[l * 4 + r], t + 1, __ATOMIC_RELEASE, SCOPE);
  }
}

extern "C" void kernel_launch(void* const* d_in, const int* in_sizes, int n_in,
                              void* d_out, int out_size, void* d_ws,
                              size_t ws_size, hipStream_t stream) {
  const float* x          = (const float*)d_in[0];
  const float* init_state = (const float*)d_in[1];
  const float* W          = (const float*)d_in[2];
  const float* bias       = (const float*)d_in[3];
  float* out = (float*)d_out;
  char* ws   = (char*)d_ws;

  init_ws<<<256, 256, 0, stream>>>(init_state, ws);
  lstm_mfma<<<256, 256, 0, stream>>>(x, init_state, W, bias, out, ws);
}

// Round 6
// 991.210 us; speedup vs baseline: 2.3277x; 1.3769x over previous
//
#include <hip/hip_runtime.h>

typedef _Float16 half8 __attribute__((ext_vector_type(8)));
typedef float f32x4 __attribute__((ext_vector_type(4)));
typedef unsigned long long ull;

#define SCOPE __HIP_MEMORY_SCOPE_AGENT

// B=16, T=64, L=64, H=256. K=2H=512, N=4H=1024. W shared across layers/time.
// ws: flags[64][4] epoch counters (int = completed timesteps for (l,r) slice),
//     then f16 h buffer: 2 slots * 64 l * 16 b * 256 u (ping-pong on t&1).
constexpr size_t OFF_FLAGS = 0;
constexpr size_t OFF_H     = 65536;

__device__ __forceinline__ size_t Hidx(int slot, int l, int b, int u) {
  return (((size_t)slot * 64 + l) * 16 + b) * 256 + u;
}
__device__ __forceinline__ float sigm(float v) { return 1.0f / (1.0f + __expf(-v)); }
__device__ __forceinline__ float tanh_(float v) { return 1.0f - 2.0f / (__expf(2.0f * v) + 1.0f); }

__global__ void init_ws(const float* __restrict__ init_state, char* ws) {
  int* flags = (int*)(ws + OFF_FLAGS);
  _Float16* Hp = (_Float16*)(ws + OFF_H);
  const int tid = blockIdx.x * 256 + threadIdx.x;  // 65536 threads
  if (tid < 4096) flags[tid] = 0;
  for (int e = tid; e < 64 * 16 * 256; e += 65536) {
    const int u = e & 255, b = (e >> 8) & 15, l = e >> 12;
    Hp[Hidx(1, l, b, u)] = (_Float16)init_state[((l * 2 + 1) * 16 + b) * 256 + u];
  }
}

// Wave-uniform sleepy poll: all 4 slices of `layer` have epoch >= need.
__device__ __forceinline__ void poll_layer(const ull* fl64, int layer, int need) {
  const ull* p = fl64 + layer * 2;
  for (int it = 0; it < (1 << 22); ++it) {
    ull p0 = __hip_atomic_load(p, __ATOMIC_RELAXED, SCOPE);
    ull p1 = __hip_atomic_load(p + 1, __ATOMIC_RELAXED, SCOPE);
    if (((int)p0 >= need) & ((int)(p0 >> 32) >= need) &
        ((int)p1 >= need) & ((int)(p1 >> 32) >= need)) return;
    __builtin_amdgcn_s_sleep(1);
  }
}

// 256 WGs = (layer l = wg>>2, col-slice r = wg&3); 1 block/CU, co-resident.
__global__ __launch_bounds__(256, 1) void lstm_mfma(
    const float* __restrict__ x, const float* __restrict__ init_state,
    const float* __restrict__ W, const float* __restrict__ bias,
    float* __restrict__ out, char* ws) {
  int* flags = (int*)(ws + OFF_FLAGS);
  ull* fl64 = (ull*)flags;
  ull* Hp64 = (ull*)(ws + OFF_H);
  unsigned short* Hp16 = (unsigned short*)(ws + OFF_H);

  const int tid = threadIdx.x;
  const int wg = blockIdx.x;
  const int l = wg >> 2, r = wg & 3;
  const int wv = tid >> 6, lane = tid & 63;

  // smem union: prologue wstage (32*257 f32 = 32896 B) aliases
  // steady-state aLds (16384 B f16 A-frags) + zLds (16*260 f32 = 16640 B).
  __shared__ __align__(16) char smem[16384 + 16640];
  float* wstage = (float*)smem;
  _Float16* aLds = (_Float16*)smem;
  float* zLds = (float*)(smem + 16384);

  // ---- W prologue: coalesced global -> LDS chunk -> f16 B-frags in registers.
  // B-frag (mfma_f32_16x16x32_f16): lane holds B[k=(lane>>4)*8+jj][n=lane&15].
  // Slice-local col nl = j*4 + g; global col = g*256 + r*64 + j.
  // NOTE: chunk loop MUST be fully unrolled — runtime index into wreg demotes
  // it to scratch (round-4: VGPR 76, 1.75 GB scratch traffic, 3x slower).
  half8 wreg[64];  // [q*16 + kb] : 4 ntiles * 16 kb
#pragma unroll
  for (int c = 0; c < 16; ++c) {  // chunk c == kb, rows k = c*32 .. c*32+31
    const float* Wc = W + (size_t)(c * 32) * 1024 + (tid >> 6) * 256 + r * 64 + (tid & 63);
#pragma unroll
    for (int rr = 0; rr < 32; ++rr)
      wstage[rr * 257 + tid] = Wc[(size_t)rr * 1024];
    __syncthreads();
#pragma unroll
    for (int q = 0; q < 4; ++q) {
      const int nl = (wv * 4 + q) * 16 + (lane & 15);
      const int pos = (nl & 3) * 64 + (nl >> 2);
      half8 hv;
#pragma unroll
      for (int jj = 0; jj < 8; ++jj)
        hv[jj] = (_Float16)wstage[((lane >> 4) * 8 + jj) * 257 + pos];
      wreg[q * 16 + c] = hv;
    }
    __syncthreads();
  }

  // ---- epilogue identity (round-3, 0-conflict): unit hu, batches b4*4+0..3 ----
  const int hu = tid & 63, b4 = tid >> 6;
  const int gu = r * 64 + hu;
  float creg[4];
#pragma unroll
  for (int bi = 0; bi < 4; ++bi)
    creg[bi] = init_state[((l * 2 + 0) * 16 + (b4 * 4 + bi)) * 256 + gu];
  const float bi_ = bias[0 * 256 + gu], bj_ = bias[1 * 256 + gu];
  const float bf_ = bias[2 * 256 + gu], bo_ = bias[3 * 256 + gu];

  for (int t = 0; t < 64; ++t) {
    const int slotCur = t & 1, slotPrev = (t + 1) & 1;

    // ---- early back-pressure load (checked just before publish) ----
    const bool bpNeed = (l < 63) && (t >= 2);
    ull bp0 = 0, bp1 = 0;
    if (bpNeed) {
      bp0 = __hip_atomic_load(fl64 + (l + 1) * 2, __ATOMIC_RELAXED, SCOPE);
      bp1 = __hip_atomic_load(fl64 + (l + 1) * 2 + 1, __ATOMIC_RELAXED, SCOPE);
    }

    // ================= phase 1: own-layer half (ready one link early) =======
    if (t > 0) poll_layer(fl64, l, t);  // siblings published h(l,t-1)

    // stage kb 8..15 cooperatively: entry e=(kb,ln): A[m=ln&15][kb*32+(ln>>4)*8+jj]
#pragma unroll
    for (int i = 0; i < 2; ++i) {
      const int e = 512 + i * 256 + tid;
      const int kb = e >> 6, ln = e & 63;
      const int m = ln & 15, k0 = (kb - 8) * 32 + ((ln >> 4) * 8);
      const size_t o = Hidx(slotPrev, l, m, k0) >> 2;
      ull a0 = __hip_atomic_load(Hp64 + o, __ATOMIC_RELAXED, SCOPE);
      ull a1 = __hip_atomic_load(Hp64 + o + 1, __ATOMIC_RELAXED, SCOPE);
      half8 hv;
      ((ull*)&hv)[0] = a0;
      ((ull*)&hv)[1] = a1;
      *(half8*)&aLds[(size_t)(kb * 64 + ln) * 8] = hv;
    }
    __syncthreads();

    f32x4 acc[4] = {{0.f, 0.f, 0.f, 0.f}, {0.f, 0.f, 0.f, 0.f},
                    {0.f, 0.f, 0.f, 0.f}, {0.f, 0.f, 0.f, 0.f}};
#pragma unroll
    for (int kb = 8; kb < 16; ++kb) {
      half8 a = *(const half8*)&aLds[(kb * 64 + lane) * 8];
#pragma unroll
      for (int q = 0; q < 4; ++q)
        acc[q] = __builtin_amdgcn_mfma_f32_16x16x32_f16(a, wreg[q * 16 + kb], acc[q], 0, 0, 0);
    }

    // ================= phase 2: producer half ===============================
    if (l > 0) poll_layer(fl64, l - 1, t + 1);  // producer published h(l-1,t)

#pragma unroll
    for (int i = 0; i < 2; ++i) {
      const int e = i * 256 + tid;
      const int kb = e >> 6, ln = e & 63;
      const int m = ln & 15, k0 = kb * 32 + ((ln >> 4) * 8);
      half8 hv;
      if (l == 0) {
        const float* xs = x + ((size_t)m * 64 + t) * 256 + k0;
        f32x4 x0 = *(const f32x4*)xs;
        f32x4 x1 = *(const f32x4*)(xs + 4);
#pragma unroll
        for (int jj = 0; jj < 4; ++jj) {
          hv[jj] = (_Float16)x0[jj];
          hv[4 + jj] = (_Float16)x1[jj];
        }
      } else {
        const size_t o = Hidx(slotCur, l - 1, m, k0) >> 2;
        ull a0 = __hip_atomic_load(Hp64 + o, __ATOMIC_RELAXED, SCOPE);
        ull a1 = __hip_atomic_load(Hp64 + o + 1, __ATOMIC_RELAXED, SCOPE);
        ((ull*)&hv)[0] = a0;
        ((ull*)&hv)[1] = a1;
      }
      *(half8*)&aLds[(size_t)(kb * 64 + ln) * 8] = hv;
    }
    __syncthreads();

#pragma unroll
    for (int kb = 0; kb < 8; ++kb) {
      half8 a = *(const half8*)&aLds[(kb * 64 + lane) * 8];
#pragma unroll
      for (int q = 0; q < 4; ++q)
        acc[q] = __builtin_amdgcn_mfma_f32_16x16x32_f16(a, wreg[q * 16 + kb], acc[q], 0, 0, 0);
    }

    // ---- z -> LDS (round-3 layout, 0-conflict): n=lane&15, mrow=(lane>>4)*4+rg
#pragma unroll
    for (int q = 0; q < 4; ++q) {
      const int nl = (wv * 4 + q) * 16 + (lane & 15);
      const int m0 = (lane >> 4) * 4;
#pragma unroll
      for (int rg = 0; rg < 4; ++rg) zLds[(m0 + rg) * 260 + nl] = acc[q][rg];
    }
    __syncthreads();

    // ---- back-pressure final check (gates slot overwrite) ----
    if (bpNeed) {
      const int need = t - 1;
      bool ok = ((int)bp0 >= need) & ((int)(bp0 >> 32) >= need) &
                ((int)bp1 >= need) & ((int)(bp1 >> 32) >= need);
      if (!ok) {
        for (int it = 0; it < (1 << 22); ++it) {
          bp0 = __hip_atomic_load(fl64 + (l + 1) * 2, __ATOMIC_RELAXED, SCOPE);
          bp1 = __hip_atomic_load(fl64 + (l + 1) * 2 + 1, __ATOMIC_RELAXED, SCOPE);
          ok = ((int)bp0 >= need) & ((int)(bp0 >> 32) >= need) &
               ((int)bp1 >= need) & ((int)(bp1 >> 32) >= need);
          if (ok) break;
          __builtin_amdgcn_s_sleep(1);
        }
      }
    }

    // ---- LSTM epilogue (round-3 pattern): thread (hu, 4 batches) ----
#pragma unroll
    for (int bi = 0; bi < 4; ++bi) {
      const int b = b4 * 4 + bi;
      f32x4 zg = *(const f32x4*)&zLds[b * 260 + hu * 4];  // (i,j,f,o) of unit hu
      const float iv = zg[0] + bi_, jv = zg[1] + bj_;
      const float fv = zg[2] + bf_, ov = zg[3] + bo_;
      const float nc = sigm(fv + 1.0f) * creg[bi] + sigm(iv) * tanh_(jv);
      const float nh = sigm(ov) * tanh_(nc);
      creg[bi] = nc;
      union { _Float16 f; unsigned short s; } cv;
      cv.f = (_Float16)nh;
      __hip_atomic_store(Hp16 + Hidx(slotCur, l, b, gu), cv.s,
                         __ATOMIC_RELAXED, SCOPE);
      if (l == 63) out[((size_t)b * 64 + t) * 256 + gu] = nh;
    }
    __syncthreads();  // drains vmcnt: all publish stores acked before flag

    if (tid == 0)
      __hip_atomic_store(&flags[l * 4 + r], t + 1, __ATOMIC_RELEASE, SCOPE);
  }
}

extern "C" void kernel_launch(void* const* d_in, const int* in_sizes, int n_in,
                              void* d_out, int out_size, void* d_ws,
                              size_t ws_size, hipStream_t stream) {
  const float* x          = (const float*)d_in[0];
  const float* init_state = (const float*)d_in[1];
  const float* W          = (const float*)d_in[2];
  const float* bias       = (const float*)d_in[3];
  float* out = (float*)d_out;
  char* ws   = (char*)d_ws;

  init_ws<<<256, 256, 0, stream>>>(init_state, ws);
  lstm_mfma<<<256, 256, 0, stream>>>(x, init_state, W, bias, out, ws);
}